// Round 2
// baseline (867243.750 us; speedup 1.0000x reference)
//
#include <hip/hip_runtime.h>
#include <hip/hip_bf16.h>
#include <math.h>
#include <stdio.h>

#define NWG 512
#define NT  256
#define B_  64
#define T_  128
#define L_  8
#define D_  512
#define HD_ 64

struct P {
  const float *data,*r,*y_d,*wte_w,*wte_b,*wpe,*ln1_w,*ln1_b,*qkv_w,*qkv_b,
              *proj_w,*proj_b,*ln2_w,*ln2_b,*fc_w,*fc_b,*mproj_w,*mproj_b,
              *lnf_w,*lnf_b,*head_w,*head_b;
  float *out, *y, *u, *hT, *qT, *oT, *gT;
  __hip_bfloat16 *Kc, *Vc;
  int *sync;
};

__device__ __forceinline__ float bf2f(unsigned u) {
  return __uint_as_float((u & 0xffffu) << 16);
}

// Tree barrier: 16 groups x 32 WGs -> root(16) -> generation bump.
// Agent-scope acq_rel atomics provide cross-XCD visibility (verified round 1).
__device__ __forceinline__ void gbar(int* sync, int wg) {
  __syncthreads();
  if (threadIdx.x == 0) {
    unsigned* gen = (unsigned*)(sync + 272);
    unsigned g0 = __hip_atomic_load(gen, __ATOMIC_RELAXED, __HIP_MEMORY_SCOPE_AGENT);
    int rr = __hip_atomic_fetch_add(sync + (wg >> 5) * 16, 1, __ATOMIC_ACQ_REL, __HIP_MEMORY_SCOPE_AGENT);
    if (rr == 31) {
      __hip_atomic_store(sync + (wg >> 5) * 16, 0, __ATOMIC_RELAXED, __HIP_MEMORY_SCOPE_AGENT);
      int rt = __hip_atomic_fetch_add(sync + 256, 1, __ATOMIC_ACQ_REL, __HIP_MEMORY_SCOPE_AGENT);
      if (rt == 15) {
        __hip_atomic_store(sync + 256, 0, __ATOMIC_RELAXED, __HIP_MEMORY_SCOPE_AGENT);
        __hip_atomic_fetch_add(gen, 1u, __ATOMIC_RELEASE, __HIP_MEMORY_SCOPE_AGENT);
      }
    }
    while (__hip_atomic_load(gen, __ATOMIC_RELAXED, __HIP_MEMORY_SCOPE_AGENT) == g0)
      __builtin_amdgcn_s_sleep(4);
    (void)__hip_atomic_load(gen, __ATOMIC_ACQUIRE, __HIP_MEMORY_SCOPE_AGENT);
  }
  __syncthreads();
}

// Row stats (mean/rstd) over hT[512][64] -> mu_s/rs_s[64].
__device__ __forceinline__ void row_stats(const float* hT, float* reda, float* redb,
                                          float* mu_s, float* rs_s) {
  const int tid = threadIdx.x, r = tid & 63, wv = tid >> 6;
  float s = 0.f, s2 = 0.f;
  #pragma unroll 8
  for (int k = wv; k < D_; k += 4) {
    const float v = hT[k * 64 + r];
    s += v; s2 += v * v;
  }
  reda[tid] = s; redb[tid] = s2;
  __syncthreads();
  if (tid < 64) {
    const float ss = reda[tid] + reda[tid + 64] + reda[tid + 128] + reda[tid + 192];
    const float q2 = redb[tid] + redb[tid + 64] + redb[tid + 128] + redb[tid + 192];
    const float mu = ss * (1.f / D_);
    const float var = q2 * (1.f / D_) - mu * mu;
    mu_s[tid] = mu; rs_s[tid] = rsqrtf(var + 1e-5f);
  }
  __syncthreads();
}

// C[:, col0..col0+CPW) += A(64xK, layout [k][r]) @ W(KxNSTR).
// wave = column group (col0 passed per-wave), lane = batch row.
template<int K, int NSTR, int CPW, bool LN>
__device__ __forceinline__ void gemm_block(const float* AT, const float* W, int col0,
                                           const float* lnw, const float* lnb,
                                           float* a_lds, const float* mu_s, const float* rs_s,
                                           float* acc_out) {
  const int tid = threadIdx.x, r = tid & 63;
  float acc[CPW], acc2[CPW];
  #pragma unroll
  for (int j = 0; j < CPW; ++j) { acc[j] = 0.f; acc2[j] = 0.f; }
  for (int kc = 0; kc < K / 128; ++kc) {
    #pragma unroll 8
    for (int ii = 0; ii < 32; ++ii) {          // stage 128x64 chunk
      const int i = tid + ii * NT;
      const int kl = i >> 6, r2 = i & 63;
      const int kg = kc * 128 + kl;
      float v = AT[kg * 64 + r2];
      if constexpr (LN) v = (v - mu_s[r2]) * rs_s[r2] * lnw[kg] + lnb[kg];
      a_lds[i] = v;
    }
    __syncthreads();
    const float* wpp = W + (size_t)(kc * 128) * NSTR + col0;
    #pragma unroll 4
    for (int kl = 0; kl < 128; kl += 2) {
      const float a0 = a_lds[kl * 64 + r];
      const float a1 = a_lds[kl * 64 + 64 + r];
      #pragma unroll
      for (int j = 0; j < CPW; ++j) {
        acc[j]  += a0 * wpp[(size_t)kl * NSTR + j];
        acc2[j] += a1 * wpp[(size_t)(kl + 1) * NSTR + j];
      }
    }
    __syncthreads();
  }
  #pragma unroll
  for (int j = 0; j < CPW; ++j) acc_out[j] = acc[j] + acc2[j];
}

__global__ __launch_bounds__(NT, 2) void gptloop(P p) {
  const int wg = blockIdx.x, tid = threadIdx.x;
  const int r = tid & 63, wv = tid >> 6;
  __shared__ float a_lds[128 * 64];
  __shared__ float reda[NT], redb[NT];
  __shared__ float mu_s[64], rs_s[64];
  __shared__ float att_s[T_];
  __shared__ float qv[64];
  __shared__ float bc[4];

  // ---- embed for st=0 + state init ----
  if (wg < B_) {
    const int row = wg;
    const float y0 = p.y_d[row * T_ * 2 + 0], y1 = p.y_d[row * T_ * 2 + 1];
    const float u0 = 191.713f, u1 = 215.888f;
    const float e0 = p.r[row * T_ * 2 + 0] - y0;
    const float e1 = p.r[row * T_ * 2 + 1] - y1;
    for (int d = tid; d < D_; d += NT) {
      const float v = e0 * p.wte_w[d] + e1 * p.wte_w[D_ + d] + u0 * p.wte_w[2 * D_ + d]
                    + u1 * p.wte_w[3 * D_ + d] + p.wte_b[d] + p.wpe[d];
      p.hT[d * 64 + row] = v;
    }
    if (tid < 2) {
      p.y[row * 2 + tid] = (tid ? y1 : y0);
      p.u[row * 2 + tid] = (tid ? u1 : u0);
    }
  }
  gbar(p.sync, wg);

  for (int st = 0; st < T_; ++st) {
    for (int l = 0; l < L_; ++l) {
      // ---- qkv GEMM [64x512]x[512x1536]: 192 WGs x 8 cols ----
      if (wg < 192) {
        row_stats(p.hT, reda, redb, mu_s, rs_s);
        float acc[2];
        const int col0 = wg * 8 + wv * 2;
        gemm_block<512, 1536, 2, true>(p.hT, p.qkv_w + (size_t)l * D_ * 1536, col0,
                                       p.ln1_w + l * D_, p.ln1_b + l * D_,
                                       a_lds, mu_s, rs_s, acc);
        #pragma unroll
        for (int j = 0; j < 2; ++j) {
          const int col = col0 + j;
          const float v = acc[j] + p.qkv_b[l * 1536 + col];
          if (col < 512) {
            p.qT[col * 64 + r] = v * 0.125f;             // fold 1/sqrt(HD)
          } else if (col < 1024) {
            const int c2 = col - 512;
            p.Kc[(((size_t)(l * B_ + r) * 8 + (c2 >> 6)) * T_ + st) * HD_ + (c2 & 63)] = __float2bfloat16(v);
          } else {
            const int c2 = col - 1024;
            p.Vc[(((size_t)(l * B_ + r) * 8 + (c2 >> 6)) * T_ + st) * HD_ + (c2 & 63)] = __float2bfloat16(v);
          }
        }
      }
      gbar(p.sync, wg);

      // ---- attention: 512 WGs, one (b,h) each ----
      {
        const int b = wg >> 3, hh = wg & 7;
        const size_t kvbase = ((size_t)(l * B_ + b) * 8 + hh) * (size_t)(T_ * HD_);
        if (tid < 64) qv[tid] = p.qT[(hh * 64 + tid) * 64 + b];
        __syncthreads();
        float s = -1e30f;
        if (tid <= st) {
          const uint4* kp = (const uint4*)(p.Kc + kvbase + (size_t)tid * HD_);
          float sc = 0.f;
          #pragma unroll
          for (int j = 0; j < 8; ++j) {
            const uint4 k4 = kp[j];
            sc += qv[j*8+0] * bf2f(k4.x) + qv[j*8+1] * bf2f(k4.x >> 16)
                + qv[j*8+2] * bf2f(k4.y) + qv[j*8+3] * bf2f(k4.y >> 16)
                + qv[j*8+4] * bf2f(k4.z) + qv[j*8+5] * bf2f(k4.z >> 16)
                + qv[j*8+6] * bf2f(k4.w) + qv[j*8+7] * bf2f(k4.w >> 16);
          }
          s = sc;
        }
        reda[tid] = s; __syncthreads();
        for (int s2 = 128; s2 >= 1; s2 >>= 1) {
          if (tid < s2) reda[tid] = fmaxf(reda[tid], reda[tid + s2]);
          __syncthreads();
        }
        const float m = reda[0];
        __syncthreads();
        const float e = (tid <= st) ? expf(s - m) : 0.f;
        if (tid < T_) att_s[tid] = e;
        reda[tid] = e; __syncthreads();
        for (int s2 = 128; s2 >= 1; s2 >>= 1) {
          if (tid < s2) reda[tid] += reda[tid + s2];
          __syncthreads();
        }
        const float inv = 1.f / reda[0];
        __syncthreads();
        float op = 0.f;
        const unsigned short* vp = (const unsigned short*)p.Vc;
        for (int t2 = wv; t2 <= st; t2 += 4)
          op += att_s[t2] * bf2f(vp[kvbase + (size_t)t2 * HD_ + r]);
        reda[tid] = op; __syncthreads();
        if (tid < 64) {
          const float o = (reda[tid] + reda[tid + 64] + reda[tid + 128] + reda[tid + 192]) * inv;
          p.oT[(hh * 64 + tid) * 64 + b] = o;
        }
      }
      gbar(p.sync, wg);

      // ---- proj GEMM [64x512]x[512x512] + residual: 64 WGs x 8 cols ----
      if (wg < 64) {
        float acc[2];
        const int col0 = wg * 8 + wv * 2;
        gemm_block<512, 512, 2, false>(p.oT, p.proj_w + (size_t)l * D_ * D_, col0,
                                       nullptr, nullptr, a_lds, nullptr, nullptr, acc);
        #pragma unroll
        for (int j = 0; j < 2; ++j) {
          const int col = col0 + j;
          p.hT[col * 64 + r] += acc[j] + p.proj_b[l * D_ + col];
        }
      }
      gbar(p.sync, wg);

      // ---- fc GEMM [64x512]x[512x2048] + gelu: 256 WGs x 8 cols ----
      if (wg < 256) {
        row_stats(p.hT, reda, redb, mu_s, rs_s);
        float acc[2];
        const int col0 = wg * 8 + wv * 2;
        gemm_block<512, 2048, 2, true>(p.hT, p.fc_w + (size_t)l * D_ * 2048, col0,
                                       p.ln2_w + l * D_, p.ln2_b + l * D_,
                                       a_lds, mu_s, rs_s, acc);
        #pragma unroll
        for (int j = 0; j < 2; ++j) {
          const int col = col0 + j;
          const float x = acc[j] + p.fc_b[l * 2048 + col];
          p.gT[(size_t)col * 64 + r] = 0.5f * x * (1.f + erff(x * 0.70710678118654752f));
        }
      }
      gbar(p.sync, wg);

      // ---- mproj GEMM [64x2048]x[2048x512] + residual: 128 WGs, wave=(colpair, khalf) ----
      if (wg < 128) {
        const int c2 = wv & 1, kh = wv >> 1;
        const float* W = p.mproj_w + (size_t)l * 2048 * D_ + wg * 4 + c2 * 2;
        float a0 = 0.f, a1 = 0.f, b0 = 0.f, b1 = 0.f;
        for (int kk = 0; kk < 16; ++kk) {
          #pragma unroll 8
          for (int ii = 0; ii < 32; ++ii) {   // stage two 64x64 sub-chunks (k and k+1024)
            const int i = tid + ii * NT;
            const int buf = i >> 12;
            const int kl = (i >> 6) & 63, r2 = i & 63;
            const int kg = buf * 1024 + kk * 64 + kl;
            a_lds[i] = p.gT[(size_t)kg * 64 + r2];
          }
          __syncthreads();
          const float* al = a_lds + (kh << 12);
          const float* wpp = W + (size_t)(kh * 1024 + kk * 64) * D_;
          #pragma unroll 4
          for (int kl = 0; kl < 64; kl += 2) {
            const float x0 = al[kl * 64 + r], x1 = al[kl * 64 + 64 + r];
            a0 += x0 * wpp[(size_t)kl * D_];
            a1 += x0 * wpp[(size_t)kl * D_ + 1];
            b0 += x1 * wpp[(size_t)(kl + 1) * D_];
            b1 += x1 * wpp[(size_t)(kl + 1) * D_ + 1];
          }
          __syncthreads();
        }
        reda[tid] = a0 + b0; redb[tid] = a1 + b1;
        __syncthreads();
        if (tid < 128) {
          const int cc = tid >> 6, rr = tid & 63;
          const int col = wg * 4 + cc * 2;
          const float t0 = reda[cc * 64 + rr] + reda[(2 + cc) * 64 + rr];
          const float t1 = redb[cc * 64 + rr] + redb[(2 + cc) * 64 + rr];
          p.hT[col * 64 + rr]       += t0 + p.mproj_b[l * D_ + col];
          p.hT[(col + 1) * 64 + rr] += t1 + p.mproj_b[l * D_ + col + 1];
        }
      }
      gbar(p.sync, wg);
    } // layers

    // ---- final: lnf + head + ODE + embed(st+1): 64 WGs, one row each ----
    if (wg < B_) {
      const int row = wg;
      const float v1 = p.hT[tid * 64 + row];
      const float v2 = p.hT[(tid + 256) * 64 + row];
      reda[tid] = v1 + v2; redb[tid] = v1 * v1 + v2 * v2;
      __syncthreads();
      for (int s2 = 128; s2 >= 1; s2 >>= 1) {
        if (tid < s2) { reda[tid] += reda[tid + s2]; redb[tid] += redb[tid + s2]; }
        __syncthreads();
      }
      const float mu = reda[0] * (1.f / D_);
      const float var = redb[0] * (1.f / D_) - mu * mu;
      const float rs = rsqrtf(var + 1e-5f);
      __syncthreads();
      const float h1 = (v1 - mu) * rs * p.lnf_w[tid] + p.lnf_b[tid];
      const float h2 = (v2 - mu) * rs * p.lnf_w[tid + 256] + p.lnf_b[tid + 256];
      reda[tid] = h1 * p.head_w[tid * 2]     + h2 * p.head_w[(tid + 256) * 2];
      redb[tid] = h1 * p.head_w[tid * 2 + 1] + h2 * p.head_w[(tid + 256) * 2 + 1];
      __syncthreads();
      for (int s2 = 128; s2 >= 1; s2 >>= 1) {
        if (tid < s2) { reda[tid] += reda[tid + s2]; redb[tid] += redb[tid + s2]; }
        __syncthreads();
      }
      if (tid < 2) {
        const float un = ((tid == 0) ? reda[0] : redb[0]) + p.head_b[tid];
        const float a  = p.data[row * 4 + tid];
        const float bb = p.data[row * 4 + 2 + tid];
        const float yv = p.y[row * 2 + tid];
        p.out[row * T_ * 2 + st * 2 + tid] = yv;
        const float yn = yv - a * yv + bb * un;
        p.y[row * 2 + tid] = yn;
        p.u[row * 2 + tid] = un;
        bc[tid] = yn; bc[2 + tid] = un;
      }
      __syncthreads();
      if (st < T_ - 1) {
        const float y0 = bc[0], y1 = bc[1], u0 = bc[2], u1 = bc[3];
        const float e0 = p.r[row * T_ * 2 + (st + 1) * 2 + 0] - y0;
        const float e1 = p.r[row * T_ * 2 + (st + 1) * 2 + 1] - y1;
        for (int d = tid; d < D_; d += NT) {
          const float v = e0 * p.wte_w[d] + e1 * p.wte_w[D_ + d] + u0 * p.wte_w[2 * D_ + d]
                        + u1 * p.wte_w[3 * D_ + d] + p.wte_b[d] + p.wpe[(st + 1) * D_ + d];
          p.hT[d * 64 + row] = v;
        }
      }
    }
    gbar(p.sync, wg);
  } // steps
}

extern "C" void kernel_launch(void* const* d_in, const int* in_sizes, int n_in,
                              void* d_out, int out_size, void* d_ws, size_t ws_size,
                              hipStream_t stream) {
  P p;
  p.data  =(const float*)d_in[0];  p.r      =(const float*)d_in[1];
  p.y_d   =(const float*)d_in[2];  p.wte_w  =(const float*)d_in[3];
  p.wte_b =(const float*)d_in[4];  p.wpe    =(const float*)d_in[5];
  p.ln1_w =(const float*)d_in[6];  p.ln1_b  =(const float*)d_in[7];
  p.qkv_w =(const float*)d_in[8];  p.qkv_b  =(const float*)d_in[9];
  p.proj_w=(const float*)d_in[10]; p.proj_b =(const float*)d_in[11];
  p.ln2_w =(const float*)d_in[12]; p.ln2_b  =(const float*)d_in[13];
  p.fc_w  =(const float*)d_in[14]; p.fc_b   =(const float*)d_in[15];
  p.mproj_w=(const float*)d_in[16];p.mproj_b=(const float*)d_in[17];
  p.lnf_w =(const float*)d_in[18]; p.lnf_b  =(const float*)d_in[19];
  p.head_w=(const float*)d_in[20]; p.head_b =(const float*)d_in[21];
  p.out = (float*)d_out;

  char* w = (char*)d_ws;
  size_t off = 0;
  p.sync=(int*)(w+off);            off += 4096;
  p.y   =(float*)(w+off);          off += 512;
  p.u   =(float*)(w+off);          off += 512;
  p.hT  =(float*)(w+off);          off += (size_t)D_*64*4;
  p.qT  =(float*)(w+off);          off += (size_t)D_*64*4;
  p.oT  =(float*)(w+off);          off += (size_t)D_*64*4;
  p.gT  =(float*)(w+off);          off += (size_t)2048*64*4;
  p.Kc  =(__hip_bfloat16*)(w+off); off += (size_t)L_*B_*8*T_*HD_*2;
  p.Vc  =(__hip_bfloat16*)(w+off); off += (size_t)L_*B_*8*T_*HD_*2;

  fprintf(stderr, "[gptloop] ws_size=%zu need=%zu\n", ws_size, off);
  if (ws_size < off) return;

  hipMemsetAsync(d_ws, 0, 4096, stream);
  hipLaunchKernelGGL(gptloop, dim3(NWG), dim3(NT), 0, stream, p);
}

// Round 3
// 158526.709 us; speedup vs baseline: 5.4706x; 5.4706x over previous
//
#include <hip/hip_runtime.h>
#include <hip/hip_bf16.h>
#include <math.h>
#include <stdio.h>

#define NWG 256
#define NT  512
#define T_  128
#define L_  8
#define D_  512

struct P {
  const float *data,*r,*y_d,*wte_w,*wte_b,*wpe,*ln1_w,*ln1_b,*qkv_w,*qkv_b,
              *proj_w,*proj_b,*ln2_w,*ln2_b,*fc_w,*fc_b,*mproj_w,*mproj_b,
              *lnf_w,*lnf_b,*head_w,*head_b;
  float *out, *y, *u, *hT, *qT, *oT, *gT;
  __hip_bfloat16 *Kc, *Vc;
  int *sync;
};

__device__ __forceinline__ float bf2f(unsigned short u) {
  return __uint_as_float(((unsigned)u) << 16);
}

// Per-group barrier: 8 sub-counters (8 WGs each) -> root(8) -> generation bump.
// sb = this group's 1KB sync region. Agent-scope acq_rel (verified r1/r2).
__device__ __forceinline__ void gbar(int* sb, int gw) {
  __syncthreads();
  if (threadIdx.x == 0) {
    unsigned* gen = (unsigned*)(sb + 144);
    unsigned g0 = __hip_atomic_load(gen, __ATOMIC_RELAXED, __HIP_MEMORY_SCOPE_AGENT);
    int rr = __hip_atomic_fetch_add(sb + (gw >> 3) * 16, 1, __ATOMIC_ACQ_REL, __HIP_MEMORY_SCOPE_AGENT);
    if (rr == 7) {
      __hip_atomic_store(sb + (gw >> 3) * 16, 0, __ATOMIC_RELAXED, __HIP_MEMORY_SCOPE_AGENT);
      int rt = __hip_atomic_fetch_add(sb + 128, 1, __ATOMIC_ACQ_REL, __HIP_MEMORY_SCOPE_AGENT);
      if (rt == 7) {
        __hip_atomic_store(sb + 128, 0, __ATOMIC_RELAXED, __HIP_MEMORY_SCOPE_AGENT);
        __hip_atomic_fetch_add(gen, 1u, __ATOMIC_RELEASE, __HIP_MEMORY_SCOPE_AGENT);
      }
    }
    while (__hip_atomic_load(gen, __ATOMIC_RELAXED, __HIP_MEMORY_SCOPE_AGENT) == g0)
      __builtin_amdgcn_s_sleep(2);
    (void)__hip_atomic_load(gen, __ATOMIC_ACQUIRE, __HIP_MEMORY_SCOPE_AGENT);
  }
  __syncthreads();
}

// Row stats over act[512][16] -> mu_s/rs_s[16]. red/red2 are scratch (>=512 each).
__device__ __forceinline__ void stats16(const float* __restrict__ act,
                                        float* red, float* red2,
                                        float* mu_s, float* rs_s) {
  const int tid = threadIdx.x;
  const int m = tid & 15, kb = tid >> 4;   // 32 k-blocks
  float s = 0.f, s2 = 0.f;
  #pragma unroll
  for (int j = 0; j < 16; ++j) {
    const float v = act[(kb + j * 32) * 16 + m];
    s += v; s2 += v * v;
  }
  red[tid] = s; red2[tid] = s2;
  __syncthreads();
  if (tid < 16) {
    float a = 0.f, b = 0.f;
    #pragma unroll 8
    for (int i = 0; i < 32; ++i) { a += red[i * 16 + tid]; b += red2[i * 16 + tid]; }
    const float mu = a * (1.f / 512.f);
    const float var = b * (1.f / 512.f) - mu * mu;
    mu_s[tid] = mu; rs_s[tid] = rsqrtf(var + 1e-5f);
  }
  __syncthreads();
}

// out[16 rows][CW cols] = act(16xKTOT, layout [k][m]) @ W(KTOTxN), cols col0..col0+CW.
// wave = k-slice of 64 (per 512-chunk), lane = (col, k-subphase). 8*SUB-way LDS reduce.
// Returns the (col0+tid>>4, tid&15) output for tid < CW*16, else 0.
template<int CW, int SUB, int KTOT, int N, bool LN>
__device__ float gemm16(const float* __restrict__ act, const float* __restrict__ W,
                        int col0, float* a_lds,
                        const float* lnw, const float* lnb,
                        const float* mu_s, const float* rs_s) {
  const int tid = threadIdx.x;
  const int lane = tid & 63, wv = tid >> 6;
  const int c = lane / SUB, ks = lane % SUB;
  float acc[16];
  #pragma unroll
  for (int m = 0; m < 16; ++m) acc[m] = 0.f;
  for (int ch = 0; ch < KTOT / 512; ++ch) {
    __syncthreads();
    #pragma unroll
    for (int jj = 0; jj < 16; ++jj) {
      const int e = tid + jj * 512;
      float v = act[ch * 8192 + e];
      if constexpr (LN) {
        const int kk = e >> 4, m = e & 15;
        v = (v - mu_s[m]) * rs_s[m] * lnw[kk] + lnb[kk];
      }
      a_lds[e] = v;
    }
    __syncthreads();
    const float* Wp = W + (size_t)(ch * 512 + wv * 64 + ks) * N + col0 + c;
    const float* ap = a_lds + (wv * 64 + ks) * 16;
    #pragma unroll 8
    for (int j = 0; j < 64 / SUB; ++j) {
      const float w0 = Wp[(size_t)j * (SUB * N)];
      const float4* a4 = (const float4*)(ap + j * (SUB * 16));
      const float4 a0 = a4[0], a1 = a4[1], a2 = a4[2], a3 = a4[3];
      acc[0]  += w0 * a0.x; acc[1]  += w0 * a0.y; acc[2]  += w0 * a0.z; acc[3]  += w0 * a0.w;
      acc[4]  += w0 * a1.x; acc[5]  += w0 * a1.y; acc[6]  += w0 * a1.z; acc[7]  += w0 * a1.w;
      acc[8]  += w0 * a2.x; acc[9]  += w0 * a2.y; acc[10] += w0 * a2.z; acc[11] += w0 * a2.w;
      acc[12] += w0 * a3.x; acc[13] += w0 * a3.y; acc[14] += w0 * a3.z; acc[15] += w0 * a3.w;
    }
  }
  __syncthreads();
  #pragma unroll
  for (int m4 = 0; m4 < 4; ++m4) {
    float4 t2; t2.x = acc[m4*4]; t2.y = acc[m4*4+1]; t2.z = acc[m4*4+2]; t2.w = acc[m4*4+3];
    *(float4*)(a_lds + tid * 16 + m4 * 4) = t2;
  }
  __syncthreads();
  float out = 0.f;
  if (tid < CW * 16) {
    const int cl = tid >> 4, m = tid & 15;
    #pragma unroll
    for (int w2 = 0; w2 < 8; ++w2)
      #pragma unroll
      for (int k2 = 0; k2 < SUB; ++k2)
        out += a_lds[(w2 * 64 + cl * SUB + k2) * 16 + m];
  }
  return out;
}

__global__ __launch_bounds__(NT, 1) void gptloop(P p) {
  const int bid = blockIdx.x, tid = threadIdx.x;
  const int g  = (bid & 7) >> 1;                 // XCD-pair group 0..3
  const int gw = (bid >> 3) * 2 + (bid & 1);     // 0..63 within group
  int* sb = p.sync + g * 256;
  float* hTg = p.hT + g * 8192;
  float* qTg = p.qT + g * 8192;
  float* oTg = p.oT + g * 8192;
  float* gTg = p.gT + g * 32768;

  __shared__ float a_lds[8192];
  __shared__ float lnw_s[512], lnb_s[512];
  __shared__ float mu_s[16], rs_s[16];
  __shared__ float att_s[2][128];
  __shared__ float qv_s[2][64];
  __shared__ float inv_s[2];
  __shared__ float bc[4];

  // ---- init: y/u state + embed(st=0) ----
  if (gw < 16) {
    const int m = gw, b = g * 16 + m;
    const float y0 = p.y_d[b * 256], y1 = p.y_d[b * 256 + 1];
    const float e0 = p.r[b * 256] - y0, e1 = p.r[b * 256 + 1] - y1;
    const float v = e0 * p.wte_w[tid] + e1 * p.wte_w[512 + tid]
                  + 191.713f * p.wte_w[1024 + tid] + 215.888f * p.wte_w[1536 + tid]
                  + p.wte_b[tid] + p.wpe[tid];
    hTg[tid * 16 + m] = v;
    if (tid < 2) {
      p.y[b * 2 + tid] = tid ? y1 : y0;
      p.u[b * 2 + tid] = tid ? 215.888f : 191.713f;
    }
  }
  gbar(sb, gw);

  for (int st = 0; st < T_; ++st) {
    for (int l = 0; l < L_; ++l) {
      // ---- qkv (+LN1): 48 WGs x 32 cols ----
      if (gw < 48) {
        lnw_s[tid] = p.ln1_w[l * 512 + tid];
        lnb_s[tid] = p.ln1_b[l * 512 + tid];
        stats16(hTg, a_lds, a_lds + 512, mu_s, rs_s);
        const float v = gemm16<32, 2, 512, 1536, true>(
            hTg, p.qkv_w + (size_t)l * 512 * 1536, gw * 32, a_lds, lnw_s, lnb_s, mu_s, rs_s);
        const int cl = tid >> 4, m = tid & 15, col = gw * 32 + cl, b = g * 16 + m;
        const float val = v + p.qkv_b[l * 1536 + col];
        if (col < 512) {
          qTg[col * 16 + m] = val * 0.125f;   // fold 1/sqrt(HD)
        } else if (col < 1024) {
          const int c2 = col - 512;
          p.Kc[((size_t)(l * 64 + b) * 8 + (c2 >> 6)) * 8192 + st * 64 + (c2 & 63)] = __float2bfloat16(val);
        } else {
          const int c2 = col - 1024;
          p.Vc[((size_t)(l * 64 + b) * 8 + (c2 >> 6)) * 8192 + st * 64 + (c2 & 63)] = __float2bfloat16(val);
        }
      }
      gbar(sb, gw);

      // ---- attention: 64 WGs x 2 (b,h) pairs ----
      {
        const int pp = tid >> 8, t = tid & 255;
        const int pid = gw * 2 + pp, bl = pid >> 3, hh = pid & 7;
        const int b = g * 16 + bl;
        const size_t kvb = ((size_t)(l * 64 + b) * 8 + hh) * (size_t)8192;
        if (t < 64) qv_s[pp][t] = qTg[(hh * 64 + t) * 16 + bl];
        __syncthreads();
        float s = -1e30f;
        if (t <= st && t < 128) {
          const uint4* kp = (const uint4*)(p.Kc + kvb + (size_t)t * 64);
          float sc = 0.f;
          #pragma unroll
          for (int j2 = 0; j2 < 8; ++j2) {
            const uint4 k4 = kp[j2];
            sc += qv_s[pp][j2*8+0] * bf2f((unsigned short)k4.x)
                + qv_s[pp][j2*8+1] * bf2f((unsigned short)(k4.x >> 16))
                + qv_s[pp][j2*8+2] * bf2f((unsigned short)k4.y)
                + qv_s[pp][j2*8+3] * bf2f((unsigned short)(k4.y >> 16))
                + qv_s[pp][j2*8+4] * bf2f((unsigned short)k4.z)
                + qv_s[pp][j2*8+5] * bf2f((unsigned short)(k4.z >> 16))
                + qv_s[pp][j2*8+6] * bf2f((unsigned short)k4.w)
                + qv_s[pp][j2*8+7] * bf2f((unsigned short)(k4.w >> 16));
          }
          s = sc;
        }
        a_lds[tid] = s; __syncthreads();
        for (int s2 = 128; s2 >= 1; s2 >>= 1) {
          if (t < s2) a_lds[pp*256 + t] = fmaxf(a_lds[pp*256 + t], a_lds[pp*256 + t + s2]);
          __syncthreads();
        }
        const float mx = a_lds[pp * 256];
        __syncthreads();
        const float e = (t <= st && t < 128) ? expf(s - mx) : 0.f;
        if (t < 128) att_s[pp][t] = e;
        a_lds[tid] = e; __syncthreads();
        for (int s2 = 128; s2 >= 1; s2 >>= 1) {
          if (t < s2) a_lds[pp*256 + t] += a_lds[pp*256 + t + s2];
          __syncthreads();
        }
        if (t == 0) inv_s[pp] = 1.f / a_lds[pp * 256];
        __syncthreads();
        const int d = t & 63, tq = t >> 6;
        float o = 0.f;
        const unsigned short* vp = (const unsigned short*)p.Vc;
        for (int tt = tq; tt <= st; tt += 4)
          o += att_s[pp][tt] * bf2f(vp[kvb + (size_t)tt * 64 + d]);
        a_lds[tid] = o; __syncthreads();
        if (tid < 128) {
          const int p2 = tid >> 6, d2 = tid & 63;
          const int pid2 = gw * 2 + p2, bl2 = pid2 >> 3, h2 = pid2 & 7;
          const float oo = (a_lds[p2*256 + d2] + a_lds[p2*256 + 64 + d2]
                          + a_lds[p2*256 + 128 + d2] + a_lds[p2*256 + 192 + d2]) * inv_s[p2];
          oTg[(h2 * 64 + d2) * 16 + bl2] = oo;
        }
      }
      gbar(sb, gw);

      // ---- proj + residual: 32 WGs x 16 cols ----
      if (gw < 32) {
        const float v = gemm16<16, 4, 512, 512, false>(
            oTg, p.proj_w + (size_t)l * 512 * 512, gw * 16, a_lds,
            nullptr, nullptr, nullptr, nullptr);
        if (tid < 256) {
          const int cl = tid >> 4, m = tid & 15, col = gw * 16 + cl;
          hTg[col * 16 + m] += v + p.proj_b[l * 512 + col];
        }
      }
      gbar(sb, gw);

      // ---- fc (+LN2) + gelu: 64 WGs x 32 cols ----
      {
        lnw_s[tid] = p.ln2_w[l * 512 + tid];
        lnb_s[tid] = p.ln2_b[l * 512 + tid];
        stats16(hTg, a_lds, a_lds + 512, mu_s, rs_s);
        const float v = gemm16<32, 2, 512, 2048, true>(
            hTg, p.fc_w + (size_t)l * 512 * 2048, gw * 32, a_lds, lnw_s, lnb_s, mu_s, rs_s);
        const int cl = tid >> 4, m = tid & 15, col = gw * 32 + cl;
        const float x = v + p.fc_b[l * 2048 + col];
        gTg[col * 16 + m] = 0.5f * x * (1.f + erff(x * 0.70710678118654752f));
      }
      gbar(sb, gw);

      // ---- mproj + residual: 32 WGs x 16 cols, K=2048 in 4 chunks ----
      if (gw < 32) {
        const float v = gemm16<16, 4, 2048, 512, false>(
            gTg, p.mproj_w + (size_t)l * 2048 * 512, gw * 16, a_lds,
            nullptr, nullptr, nullptr, nullptr);
        if (tid < 256) {
          const int cl = tid >> 4, m = tid & 15, col = gw * 16 + cl;
          hTg[col * 16 + m] += v + p.mproj_b[l * 512 + col];
        }
      }
      gbar(sb, gw);
    } // layers

    // ---- final: lnf + head + ODE + out + embed(st+1): 16 WGs, one row each ----
    if (gw < 16) {
      const int m = gw, b = g * 16 + m;
      const float v = hTg[tid * 16 + m];
      a_lds[tid] = v; a_lds[512 + tid] = v * v;
      __syncthreads();
      for (int s2 = 256; s2 >= 1; s2 >>= 1) {
        if (tid < s2) { a_lds[tid] += a_lds[tid + s2]; a_lds[512 + tid] += a_lds[512 + tid + s2]; }
        __syncthreads();
      }
      const float mu = a_lds[0] * (1.f / 512.f);
      const float var = a_lds[512] * (1.f / 512.f) - mu * mu;
      const float rs = rsqrtf(var + 1e-5f);
      __syncthreads();
      const float hf = (v - mu) * rs * p.lnf_w[tid] + p.lnf_b[tid];
      a_lds[tid] = hf * p.head_w[tid * 2];
      a_lds[512 + tid] = hf * p.head_w[tid * 2 + 1];
      __syncthreads();
      for (int s2 = 256; s2 >= 1; s2 >>= 1) {
        if (tid < s2) { a_lds[tid] += a_lds[tid + s2]; a_lds[512 + tid] += a_lds[512 + tid + s2]; }
        __syncthreads();
      }
      if (tid < 2) {
        const float un = ((tid == 0) ? a_lds[0] : a_lds[512]) + p.head_b[tid];
        const float a  = p.data[b * 4 + tid];
        const float bb = p.data[b * 4 + 2 + tid];
        const float yv = p.y[b * 2 + tid];
        p.out[b * 256 + st * 2 + tid] = yv;
        const float yn = yv - a * yv + bb * un;
        p.y[b * 2 + tid] = yn;
        p.u[b * 2 + tid] = un;
        bc[tid] = yn; bc[2 + tid] = un;
      }
      __syncthreads();
      if (st < T_ - 1) {
        const float e0 = p.r[b * 256 + (st + 1) * 2]     - bc[0];
        const float e1 = p.r[b * 256 + (st + 1) * 2 + 1] - bc[1];
        const float v2 = e0 * p.wte_w[tid] + e1 * p.wte_w[512 + tid]
                       + bc[2] * p.wte_w[1024 + tid] + bc[3] * p.wte_w[1536 + tid]
                       + p.wte_b[tid] + p.wpe[(st + 1) * 512 + tid];
        hTg[tid * 16 + m] = v2;
      }
    }
    gbar(sb, gw);
  } // steps
}

extern "C" void kernel_launch(void* const* d_in, const int* in_sizes, int n_in,
                              void* d_out, int out_size, void* d_ws, size_t ws_size,
                              hipStream_t stream) {
  P p;
  p.data  =(const float*)d_in[0];  p.r      =(const float*)d_in[1];
  p.y_d   =(const float*)d_in[2];  p.wte_w  =(const float*)d_in[3];
  p.wte_b =(const float*)d_in[4];  p.wpe    =(const float*)d_in[5];
  p.ln1_w =(const float*)d_in[6];  p.ln1_b  =(const float*)d_in[7];
  p.qkv_w =(const float*)d_in[8];  p.qkv_b  =(const float*)d_in[9];
  p.proj_w=(const float*)d_in[10]; p.proj_b =(const float*)d_in[11];
  p.ln2_w =(const float*)d_in[12]; p.ln2_b  =(const float*)d_in[13];
  p.fc_w  =(const float*)d_in[14]; p.fc_b   =(const float*)d_in[15];
  p.mproj_w=(const float*)d_in[16];p.mproj_b=(const float*)d_in[17];
  p.lnf_w =(const float*)d_in[18]; p.lnf_b  =(const float*)d_in[19];
  p.head_w=(const float*)d_in[20]; p.head_b =(const float*)d_in[21];
  p.out = (float*)d_out;

  char* w = (char*)d_ws;
  size_t off = 0;
  p.sync=(int*)(w+off);            off += 4096;
  p.y   =(float*)(w+off);          off += 512;
  p.u   =(float*)(w+off);          off += 512;
  p.hT  =(float*)(w+off);          off += (size_t)4*8192*4;
  p.qT  =(float*)(w+off);          off += (size_t)4*8192*4;
  p.oT  =(float*)(w+off);          off += (size_t)4*8192*4;
  p.gT  =(float*)(w+off);          off += (size_t)4*32768*4;
  p.Kc  =(__hip_bfloat16*)(w+off); off += (size_t)L_*64*8*T_*64*2;
  p.Vc  =(__hip_bfloat16*)(w+off); off += (size_t)L_*64*8*T_*64*2;

  fprintf(stderr, "[gptloop] ws_size=%zu need=%zu\n", ws_size, off);
  if (ws_size < off) return;

  hipMemsetAsync(d_ws, 0, 4096, stream);
  hipLaunchKernelGGL(gptloop, dim3(NWG), dim3(NT), 0, stream, p);
}

// Round 4
// 132074.268 us; speedup vs baseline: 6.5663x; 1.2003x over previous
//
#include <hip/hip_runtime.h>
#include <hip/hip_bf16.h>
#include <math.h>
#include <stdio.h>

#define NWG 128
#define NT  512
#define T_  128
#define L_  8

struct P {
  const float *data,*r,*y_d,*wte_w,*wte_b,*wpe,*ln1_w,*ln1_b,*qkv_w,*qkv_b,
              *proj_w,*proj_b,*ln2_w,*ln2_b,*fc_w,*fc_b,*mproj_w,*mproj_b,
              *lnf_w,*lnf_b,*head_w,*head_b;
  float *out, *y, *u, *hT, *oT, *gT;
  __hip_bfloat16 *Kc, *Vc;
  int *sync;
};

__device__ __forceinline__ float bf2f(unsigned short u) {
  return __uint_as_float(((unsigned)u) << 16);
}

// Single-level 32-arrival barrier per group. counter sb[0], generation sb[32]
// (separate 128B lines). Agent-scope acq_rel (cross-XCD verified r1-r3).
__device__ __forceinline__ void gbar(int* sb) {
  __syncthreads();
  if (threadIdx.x == 0) {
    unsigned* gen = (unsigned*)(sb + 32);
    unsigned g0 = __hip_atomic_load(gen, __ATOMIC_RELAXED, __HIP_MEMORY_SCOPE_AGENT);
    int r = __hip_atomic_fetch_add(sb, 1, __ATOMIC_ACQ_REL, __HIP_MEMORY_SCOPE_AGENT);
    if (r == 31) {
      __hip_atomic_store(sb, 0, __ATOMIC_RELAXED, __HIP_MEMORY_SCOPE_AGENT);
      __hip_atomic_fetch_add(gen, 1u, __ATOMIC_RELEASE, __HIP_MEMORY_SCOPE_AGENT);
    }
    while (__hip_atomic_load(gen, __ATOMIC_RELAXED, __HIP_MEMORY_SCOPE_AGENT) == g0)
      __builtin_amdgcn_s_sleep(4);
    (void)__hip_atomic_load(gen, __ATOMIC_ACQUIRE, __HIP_MEMORY_SCOPE_AGENT);
  }
  __syncthreads();
}

// Row stats (mean/rstd) over act[512][16] -> mu_s/rs_s[16].
__device__ __forceinline__ void stats16(const float* __restrict__ act,
                                        float* red, float* red2,
                                        float* mu_s, float* rs_s) {
  const int tid = threadIdx.x;
  const int m = tid & 15, kb = tid >> 4;
  float s = 0.f, s2 = 0.f;
  #pragma unroll
  for (int j = 0; j < 16; ++j) {
    const float v = act[(kb + j * 32) * 16 + m];
    s += v; s2 += v * v;
  }
  red[tid] = s; red2[tid] = s2;
  __syncthreads();
  if (tid < 16) {
    float a = 0.f, b = 0.f;
    #pragma unroll 8
    for (int i = 0; i < 32; ++i) { a += red[i * 16 + tid]; b += red2[i * 16 + tid]; }
    const float mu = a * (1.f / 512.f);
    const float var = b * (1.f / 512.f) - mu * mu;
    mu_s[tid] = mu; rs_s[tid] = rsqrtf(var + 1e-5f);
  }
  __syncthreads();
}

// Stage one 512x16 fp32 slab of A into LDS (optional LayerNorm fused).
template<bool LN>
__device__ __forceinline__ void stageA(const float* __restrict__ act, int ch, float* a_lds,
                                       const float* __restrict__ lnw, const float* __restrict__ lnb,
                                       const float* mu_s, const float* rs_s) {
  const int tid = threadIdx.x;
  #pragma unroll
  for (int jj = 0; jj < 16; ++jj) {
    const int e = tid + jj * 512;
    float v = act[ch * 8192 + e];
    if constexpr (LN) {
      const int kk = e >> 4, m = e & 15;
      v = (v - mu_s[m]) * rs_s[m] * lnw[kk] + lnb[kk];
    }
    a_lds[e] = v;
  }
}

// One 512-k chunk: acc[2cols][16rows] += A(16x512 in LDS) @ W[512][N] cols col0+cg*2.
// lane: s=k-subrow(2), cg=col-pair(32); wave: 64-k slice. 8-deep load batches.
__device__ __forceinline__ void gemm_core(const float* __restrict__ W, int N, int col0,
                                          const float* __restrict__ a_lds,
                                          float* acc0, float* acc1) {
  const int tid = threadIdx.x;
  const int wv = tid >> 6, lane = tid & 63;
  const int s = lane >> 5, cg = lane & 31;
  const float* Wp = W + (size_t)(wv * 64 + s) * N + col0 + cg * 2;
  const float* ap = a_lds + (wv * 64 + s) * 16;
  for (int jb = 0; jb < 4; ++jb) {
    float2 w[8];
    #pragma unroll
    for (int u = 0; u < 8; ++u)
      w[u] = *(const float2*)(Wp + (size_t)((jb * 8 + u) * 2) * N);
    #pragma unroll
    for (int u = 0; u < 8; ++u) {
      const float4* a4 = (const float4*)(ap + (jb * 8 + u) * 32);
      const float4 a0 = a4[0], a1 = a4[1], a2 = a4[2], a3 = a4[3];
      const float wx = w[u].x, wy = w[u].y;
      acc0[0]+=wx*a0.x; acc0[1]+=wx*a0.y; acc0[2]+=wx*a0.z; acc0[3]+=wx*a0.w;
      acc0[4]+=wx*a1.x; acc0[5]+=wx*a1.y; acc0[6]+=wx*a1.z; acc0[7]+=wx*a1.w;
      acc0[8]+=wx*a2.x; acc0[9]+=wx*a2.y; acc0[10]+=wx*a2.z; acc0[11]+=wx*a2.w;
      acc0[12]+=wx*a3.x; acc0[13]+=wx*a3.y; acc0[14]+=wx*a3.z; acc0[15]+=wx*a3.w;
      acc1[0]+=wy*a0.x; acc1[1]+=wy*a0.y; acc1[2]+=wy*a0.z; acc1[3]+=wy*a0.w;
      acc1[4]+=wy*a1.x; acc1[5]+=wy*a1.y; acc1[6]+=wy*a1.z; acc1[7]+=wy*a1.w;
      acc1[8]+=wy*a2.x; acc1[9]+=wy*a2.y; acc1[10]+=wy*a2.z; acc1[11]+=wy*a2.w;
      acc1[12]+=wy*a3.x; acc1[13]+=wy*a3.y; acc1[14]+=wy*a3.z; acc1[15]+=wy*a3.w;
    }
  }
}

// Cross-lane (xor32) + cross-wave (LDS, pad-17) reduce -> per-thread 2 outputs
// for (col = col0 + (tid>>4)*2 + {0,1}, m = tid&15).
__device__ __forceinline__ float2 reduce_out(float* acc0, float* acc1, float* red_lds) {
  const int tid = threadIdx.x;
  const int wv = tid >> 6, lane = tid & 63, cg = lane & 31;
  __syncthreads();
  #pragma unroll
  for (int m = 0; m < 16; ++m) {
    acc0[m] += __shfl_xor(acc0[m], 32);
    acc1[m] += __shfl_xor(acc1[m], 32);
  }
  if (lane < 32) {
    float* rp = red_lds + (size_t)(wv * 64 + cg * 2) * 17;
    #pragma unroll
    for (int m = 0; m < 16; ++m) { rp[m] = acc0[m]; rp[17 + m] = acc1[m]; }
  }
  __syncthreads();
  const int cpair = tid >> 4, m = tid & 15;
  float o0 = 0.f, o1 = 0.f;
  #pragma unroll
  for (int w2 = 0; w2 < 8; ++w2) {
    o0 += red_lds[(size_t)(w2 * 64 + cpair * 2) * 17 + m];
    o1 += red_lds[(size_t)(w2 * 64 + cpair * 2 + 1) * 17 + m];
  }
  return make_float2(o0, o1);
}

__global__ __launch_bounds__(NT, 1) void gptloop(P p) {
  const int bid = blockIdx.x, tid = threadIdx.x;
  const int g  = (bid & 7) >> 1;              // XCD-pair group 0..3, 16 rows each
  const int gw = (bid >> 3) * 2 + (bid & 1);  // 0..31 within group
  int* sb = p.sync + g * 64;
  float* hTg = p.hT + g * 8192;
  float* oTg = p.oT + g * 8192;
  float* gTg = p.gT + g * 32768;

  __shared__ float a_lds[8192];
  __shared__ float red_lds[8704];
  __shared__ float q_s[1024];
  __shared__ float att_lds[2048];
  __shared__ float mu_s[16], rs_s[16], bc[4];

  // ---- init: y/u state + embed(st=0), 16 WGs x 1 row ----
  if (gw < 16) {
    const int m = gw, b = g * 16 + m;
    const float y0 = p.y_d[b * 256], y1 = p.y_d[b * 256 + 1];
    const float e0 = p.r[b * 256] - y0, e1 = p.r[b * 256 + 1] - y1;
    const float v = e0 * p.wte_w[tid] + e1 * p.wte_w[512 + tid]
                  + 191.713f * p.wte_w[1024 + tid] + 215.888f * p.wte_w[1536 + tid]
                  + p.wte_b[tid] + p.wpe[tid];
    hTg[tid * 16 + m] = v;
    if (tid < 2) {
      p.y[b * 2 + tid] = tid ? y1 : y0;
      p.u[b * 2 + tid] = tid ? 215.888f : 191.713f;
    }
  }
  gbar(sb);

  for (int st = 0; st < T_; ++st) {
    for (int l = 0; l < L_; ++l) {
      // ---- fused qkv (+LN1) + attention: 8 WGs, one head each ----
      if (gw < 8) {
        const int h = gw;
        stats16(hTg, red_lds, red_lds + 512, mu_s, rs_s);
        stageA<true>(hTg, 0, a_lds, p.ln1_w + l * 512, p.ln1_b + l * 512, mu_s, rs_s);
        __syncthreads();
        const float* Wq = p.qkv_w + (size_t)l * 512 * 1536;
        #pragma unroll
        for (int blk = 0; blk < 3; ++blk) {
          const int col0 = blk * 512 + h * 64;
          float acc0[16], acc1[16];
          #pragma unroll
          for (int m = 0; m < 16; ++m) { acc0[m] = 0.f; acc1[m] = 0.f; }
          gemm_core(Wq, 1536, col0, a_lds, acc0, acc1);
          const float2 o = reduce_out(acc0, acc1, red_lds);
          const int cpair = tid >> 4, m = tid & 15;
          const int b = g * 16 + m;
          #pragma unroll
          for (int j2 = 0; j2 < 2; ++j2) {
            const int cl = cpair * 2 + j2;
            const float v = ((j2 == 0) ? o.x : o.y) + p.qkv_b[l * 1536 + col0 + cl];
            if (blk == 0) q_s[m * 64 + cl] = v * 0.125f;   // fold 1/sqrt(HD)
            else {
              __hip_bfloat16* dst = (blk == 1) ? p.Kc : p.Vc;
              dst[((size_t)(l * 64 + b) * 8 + h) * 8192 + st * 64 + cl] = __float2bfloat16(v);
            }
          }
        }
        __syncthreads();   // q_s + K/V(st) visible to whole WG
        const int b16 = tid >> 5, l32 = tid & 31;
        const size_t kvb = ((size_t)(l * 64 + g * 16 + b16) * 8 + h) * 8192;
        float sc[4];
        #pragma unroll
        for (int it = 0; it < 4; ++it) {
          const int t = l32 + it * 32;
          float sv = -1e30f;
          if (t <= st) {
            const uint4* kp = (const uint4*)((const unsigned short*)p.Kc + kvb + (size_t)t * 64);
            uint4 kq[8];
            #pragma unroll
            for (int j2 = 0; j2 < 8; ++j2) kq[j2] = kp[j2];
            float acc = 0.f;
            #pragma unroll
            for (int j2 = 0; j2 < 8; ++j2) {
              const float4 qa = *(const float4*)(q_s + b16 * 64 + j2 * 8);
              const float4 qb = *(const float4*)(q_s + b16 * 64 + j2 * 8 + 4);
              acc += qa.x * bf2f((unsigned short)kq[j2].x) + qa.y * bf2f((unsigned short)(kq[j2].x >> 16))
                   + qa.z * bf2f((unsigned short)kq[j2].y) + qa.w * bf2f((unsigned short)(kq[j2].y >> 16))
                   + qb.x * bf2f((unsigned short)kq[j2].z) + qb.y * bf2f((unsigned short)(kq[j2].z >> 16))
                   + qb.z * bf2f((unsigned short)kq[j2].w) + qb.w * bf2f((unsigned short)(kq[j2].w >> 16));
            }
            sv = acc;
          }
          sc[it] = sv;
        }
        float mx = fmaxf(fmaxf(sc[0], sc[1]), fmaxf(sc[2], sc[3]));
        #pragma unroll
        for (int mk = 1; mk < 32; mk <<= 1) mx = fmaxf(mx, __shfl_xor(mx, mk, 32));
        float se = 0.f;
        #pragma unroll
        for (int it = 0; it < 4; ++it) {
          const int t = l32 + it * 32;
          const float e = (t <= st) ? expf(sc[it] - mx) : 0.f;
          att_lds[b16 * 128 + t] = e;
          se += e;
        }
        #pragma unroll
        for (int mk = 1; mk < 32; mk <<= 1) se += __shfl_xor(se, mk, 32);
        const float inv = 1.f / se;
        __syncthreads();
        const int d2 = l32 * 2;
        float o0 = 0.f, o1 = 0.f;
        const unsigned short* vp = (const unsigned short*)p.Vc + kvb;
        for (int t = 0; t <= st; ++t) {
          const float a = att_lds[b16 * 128 + t];
          const unsigned vv = *(const unsigned*)(vp + (size_t)t * 64 + d2);
          o0 += a * bf2f((unsigned short)vv);
          o1 += a * bf2f((unsigned short)(vv >> 16));
        }
        oTg[(h * 64 + d2) * 16 + b16]     = o0 * inv;
        oTg[(h * 64 + d2 + 1) * 16 + b16] = o1 * inv;
      }
      gbar(sb);

      // ---- proj + residual: 8 WGs x 64 cols ----
      if (gw < 8) {
        stageA<false>(oTg, 0, a_lds, nullptr, nullptr, nullptr, nullptr);
        __syncthreads();
        float acc0[16], acc1[16];
        #pragma unroll
        for (int m = 0; m < 16; ++m) { acc0[m] = 0.f; acc1[m] = 0.f; }
        gemm_core(p.proj_w + (size_t)l * 512 * 512, 512, gw * 64, a_lds, acc0, acc1);
        const float2 o = reduce_out(acc0, acc1, red_lds);
        const int cpair = tid >> 4, m = tid & 15;
        const int col = gw * 64 + cpair * 2;
        hTg[col * 16 + m]       += o.x + p.proj_b[l * 512 + col];
        hTg[(col + 1) * 16 + m] += o.y + p.proj_b[l * 512 + col + 1];
      }
      gbar(sb);

      // ---- fc (+LN2) + gelu: 32 WGs x 64 cols ----
      {
        stats16(hTg, red_lds, red_lds + 512, mu_s, rs_s);
        stageA<true>(hTg, 0, a_lds, p.ln2_w + l * 512, p.ln2_b + l * 512, mu_s, rs_s);
        __syncthreads();
        float acc0[16], acc1[16];
        #pragma unroll
        for (int m = 0; m < 16; ++m) { acc0[m] = 0.f; acc1[m] = 0.f; }
        gemm_core(p.fc_w + (size_t)l * 512 * 2048, 2048, gw * 64, a_lds, acc0, acc1);
        const float2 o = reduce_out(acc0, acc1, red_lds);
        const int cpair = tid >> 4, m = tid & 15;
        const int col = gw * 64 + cpair * 2;
        const float x0 = o.x + p.fc_b[l * 2048 + col];
        const float x1 = o.y + p.fc_b[l * 2048 + col + 1];
        gTg[col * 16 + m]       = 0.5f * x0 * (1.f + erff(x0 * 0.70710678118654752f));
        gTg[(col + 1) * 16 + m] = 0.5f * x1 * (1.f + erff(x1 * 0.70710678118654752f));
      }
      gbar(sb);

      // ---- mproj + residual: 8 WGs x 64 cols, K=2048 in 4 chunks ----
      if (gw < 8) {
        float acc0[16], acc1[16];
        #pragma unroll
        for (int m = 0; m < 16; ++m) { acc0[m] = 0.f; acc1[m] = 0.f; }
        for (int ch = 0; ch < 4; ++ch) {
          __syncthreads();
          stageA<false>(gTg, ch, a_lds, nullptr, nullptr, nullptr, nullptr);
          __syncthreads();
          gemm_core(p.mproj_w + (size_t)l * 2048 * 512 + (size_t)ch * 512 * 512,
                    512, gw * 64, a_lds, acc0, acc1);
        }
        const float2 o = reduce_out(acc0, acc1, red_lds);
        const int cpair = tid >> 4, m = tid & 15;
        const int col = gw * 64 + cpair * 2;
        hTg[col * 16 + m]       += o.x + p.mproj_b[l * 512 + col];
        hTg[(col + 1) * 16 + m] += o.y + p.mproj_b[l * 512 + col + 1];
      }
      gbar(sb);
    } // layers

    // ---- final: lnf + head + ODE + out + embed(st+1): 16 WGs x 1 row ----
    if (gw < 16) {
      const int m = gw, b = g * 16 + m;
      const float v = hTg[tid * 16 + m];
      a_lds[tid] = v; a_lds[512 + tid] = v * v;
      __syncthreads();
      for (int s2 = 256; s2 >= 1; s2 >>= 1) {
        if (tid < s2) { a_lds[tid] += a_lds[tid + s2]; a_lds[512 + tid] += a_lds[512 + tid + s2]; }
        __syncthreads();
      }
      const float mu = a_lds[0] * (1.f / 512.f);
      const float var = a_lds[512] * (1.f / 512.f) - mu * mu;
      const float rs = rsqrtf(var + 1e-5f);
      __syncthreads();
      const float hf = (v - mu) * rs * p.lnf_w[tid] + p.lnf_b[tid];
      a_lds[tid] = hf * p.head_w[tid * 2];
      a_lds[512 + tid] = hf * p.head_w[tid * 2 + 1];
      __syncthreads();
      for (int s2 = 256; s2 >= 1; s2 >>= 1) {
        if (tid < s2) { a_lds[tid] += a_lds[tid + s2]; a_lds[512 + tid] += a_lds[512 + tid + s2]; }
        __syncthreads();
      }
      if (tid < 2) {
        const float un = ((tid == 0) ? a_lds[0] : a_lds[512]) + p.head_b[tid];
        const float a  = p.data[b * 4 + tid];
        const float bb = p.data[b * 4 + 2 + tid];
        const float yv = p.y[b * 2 + tid];
        p.out[b * 256 + st * 2 + tid] = yv;
        const float yn = yv - a * yv + bb * un;
        p.y[b * 2 + tid] = yn;
        p.u[b * 2 + tid] = un;
        bc[tid] = yn; bc[2 + tid] = un;
      }
      __syncthreads();
      if (st < T_ - 1) {
        const float e0 = p.r[b * 256 + (st + 1) * 2]     - bc[0];
        const float e1 = p.r[b * 256 + (st + 1) * 2 + 1] - bc[1];
        const float v2 = e0 * p.wte_w[tid] + e1 * p.wte_w[512 + tid]
                       + bc[2] * p.wte_w[1024 + tid] + bc[3] * p.wte_w[1536 + tid]
                       + p.wte_b[tid] + p.wpe[(st + 1) * 512 + tid];
        hTg[tid * 16 + m] = v2;
      }
    }
    gbar(sb);
  } // steps
}

extern "C" void kernel_launch(void* const* d_in, const int* in_sizes, int n_in,
                              void* d_out, int out_size, void* d_ws, size_t ws_size,
                              hipStream_t stream) {
  P p;
  p.data  =(const float*)d_in[0];  p.r      =(const float*)d_in[1];
  p.y_d   =(const float*)d_in[2];  p.wte_w  =(const float*)d_in[3];
  p.wte_b =(const float*)d_in[4];  p.wpe    =(const float*)d_in[5];
  p.ln1_w =(const float*)d_in[6];  p.ln1_b  =(const float*)d_in[7];
  p.qkv_w =(const float*)d_in[8];  p.qkv_b  =(const float*)d_in[9];
  p.proj_w=(const float*)d_in[10]; p.proj_b =(const float*)d_in[11];
  p.ln2_w =(const float*)d_in[12]; p.ln2_b  =(const float*)d_in[13];
  p.fc_w  =(const float*)d_in[14]; p.fc_b   =(const float*)d_in[15];
  p.mproj_w=(const float*)d_in[16];p.mproj_b=(const float*)d_in[17];
  p.lnf_w =(const float*)d_in[18]; p.lnf_b  =(const float*)d_in[19];
  p.head_w=(const float*)d_in[20]; p.head_b =(const float*)d_in[21];
  p.out = (float*)d_out;

  char* w = (char*)d_ws;
  size_t off = 0;
  p.sync=(int*)(w+off);            off += 4096;
  p.y   =(float*)(w+off);          off += 512;
  p.u   =(float*)(w+off);          off += 512;
  p.hT  =(float*)(w+off);          off += (size_t)4*8192*4;
  p.oT  =(float*)(w+off);          off += (size_t)4*8192*4;
  p.gT  =(float*)(w+off);          off += (size_t)4*32768*4;
  p.Kc  =(__hip_bfloat16*)(w+off); off += (size_t)L_*64*8*T_*64*2;
  p.Vc  =(__hip_bfloat16*)(w+off); off += (size_t)L_*64*8*T_*64*2;

  fprintf(stderr, "[gptloop] ws_size=%zu need=%zu\n", ws_size, off);
  if (ws_size < off) return;

  hipMemsetAsync(d_ws, 0, 4096, stream);
  hipLaunchKernelGGL(gptloop, dim3(NWG), dim3(NT), 0, stream, p);
}